// Round 4
// baseline (488.049 us; speedup 1.0000x reference)
//
#include <hip/hip_runtime.h>
#include <cstdint>

// SpacetimeNonLocalBlock: B=4, C=256, T*H*W=N=6272, IC=128.
// R11: flash9 = flash5's proven memory structure (reg-staged V, padded
// [128][36] V, one __syncthreads/iter whose implicit vmcnt(0) gives a full
// iteration of load hiding) + within-wave S-ahead pipeline: body(t) computes
// QK(t+1) [matrix pipe] concurrently with softmax(t) [VALU/TRANS] then PV(t).
// 3 LDS buffers, statically indexed via unroll-6 (48 = 6*8 steady bodies +
// prologue QK(0) + epilogue tile 48). K staged by global_load_lds w=16 with
// pre-swizzled source (same LDS image as flash5's swizzled store). XCD-slab
// swizzle kept from R9 (FETCH 66->25MB). No setprio/sched_barrier/asm-vmcnt
// (R10 showed they inflate VGPR and kill occupancy). accS ping-pong (A/B).

#define BB   4
#define CCH  256
#define NPOS 6272
#define ICH  128
#define BNIC ((size_t)BB * NPOS * ICH)
#define KSPL 4
#define KLEN (NPOS / KSPL)   // 1568
#define TKF  32
#define NITK (KLEN / TKF)    // 49
#define SLACK 12.0f

typedef __attribute__((ext_vector_type(8)))  _Float16 h8v;  // 8 f16 MFMA frag
typedef __attribute__((ext_vector_type(16))) float fx16;    // 32x32 acc

__device__ __forceinline__ unsigned short f2h(float f) {
  _Float16 h = (_Float16)f;
  return __builtin_bit_cast(unsigned short, h);
}
__device__ __forceinline__ unsigned int pkh(float lo, float hi) {
  return __builtin_bit_cast(unsigned int, __builtin_amdgcn_cvt_pkrtz(lo, hi));
}

// ---------------------------------------------------------------------------
// proj_qkv: fused Q/K/V projections. grid (N/64, B); block 256.
// ---------------------------------------------------------------------------
__global__ __launch_bounds__(256, 1)
void proj_qkv(const float* __restrict__ x,
              const float* __restrict__ Wtheta,
              const float* __restrict__ Wphi,
              const float* __restrict__ Wg,
              unsigned short* __restrict__ Qg,
              unsigned short* __restrict__ Kg,
              unsigned short* __restrict__ Vtg) {
  const int n0 = blockIdx.x * 64;
  const int b  = blockIdx.y;
  __shared__ float Xt[16][68];      // [k][n]
  __shared__ float Wt[6][16][68];   // [tile][k][o]
  const int tid = threadIdx.x;
  const int tx = tid & 15, ty = tid >> 4;
  float acc[6][4][4] = {};          // [tile][n_i][o_j]
  const float* Ws[3] = {Wtheta, Wphi, Wg};

  for (int c0 = 0; c0 < CCH; c0 += 16) {
    {
      const int nn = tid & 63, k4 = tid >> 6;
      #pragma unroll
      for (int q = 0; q < 4; ++q) {
        const int kk = k4 + q * 4;
        Xt[kk][nn] = x[((size_t)(b * CCH + c0 + kk)) * NPOS + n0 + nn];
      }
      const int wk = tid & 15, wo = tid >> 4;
      #pragma unroll
      for (int w = 0; w < 6; ++w) {
        const float* W = Ws[w >> 1];
        const int o_half = (w & 1) * 64;
        #pragma unroll
        for (int q = 0; q < 4; ++q) {
          const int oo = wo + q * 16;
          Wt[w][wk][oo] = W[(size_t)(o_half + oo) * CCH + c0 + wk];
        }
      }
    }
    __syncthreads();
    #pragma unroll
    for (int kk = 0; kk < 16; ++kk) {
      const float4 av = *(const float4*)&Xt[kk][ty * 4];
      const float a_[4] = {av.x, av.y, av.z, av.w};
      #pragma unroll
      for (int w = 0; w < 6; ++w) {
        const float4 bv = *(const float4*)&Wt[w][kk][tx * 4];
        const float b_[4] = {bv.x, bv.y, bv.z, bv.w};
        #pragma unroll
        for (int i = 0; i < 4; ++i)
          #pragma unroll
          for (int j = 0; j < 4; ++j) acc[w][i][j] += a_[i] * b_[j];
      }
    }
    __syncthreads();
  }

  const float LOG2E = 1.4426950408889634f;
  #pragma unroll
  for (int w = 0; w < 4; ++w) {
    const int o_half = (w & 1) * 64;
    unsigned short* Out = (w < 2) ? Qg : Kg;
    const float scl = (w < 2) ? LOG2E : 1.0f;
    #pragma unroll
    for (int i = 0; i < 4; ++i) {
      ushort4 v;
      v.x = f2h(acc[w][i][0] * scl); v.y = f2h(acc[w][i][1] * scl);
      v.z = f2h(acc[w][i][2] * scl); v.w = f2h(acc[w][i][3] * scl);
      *(ushort4*)&Out[((size_t)b * NPOS + n0 + ty * 4 + i) * ICH + o_half + tx * 4] = v;
    }
  }
  #pragma unroll
  for (int w = 4; w < 6; ++w) {
    const int o_half = (w & 1) * 64;
    #pragma unroll
    for (int j = 0; j < 4; ++j) {
      const int o = o_half + tx * 4 + j;
      ushort4 v;
      v.x = f2h(acc[w][0][j]); v.y = f2h(acc[w][1][j]);
      v.z = f2h(acc[w][2][j]); v.w = f2h(acc[w][3][j]);
      *(ushort4*)&Vtg[((size_t)b * ICH + o) * NPOS + n0 + ty * 4] = v;
    }
  }
}

// ---------------------------------------------------------------------------
// flash9: flat grid 784 = 8 XCD * 2 slabs * 49 n-tiles; 4 waves, q=32/wave.
// S-ahead: QK(t+1) overlaps softmax(t). 3 bufs (51 KB), unroll-6 static idx.
// ---------------------------------------------------------------------------
#define STAGEK(STG)                                                            \
  {                                                                            \
    __builtin_amdgcn_global_load_lds(                                          \
      (const __attribute__((address_space(1))) void*)&Kg[kOff0],               \
      (__attribute__((address_space(3))) void*)&Ks[STG][(wv * 2 + 0) * 512],   \
      16, 0, 0);                                                               \
    __builtin_amdgcn_global_load_lds(                                          \
      (const __attribute__((address_space(1))) void*)&Kg[kOff1],               \
      (__attribute__((address_space(3))) void*)&Ks[STG][(wv * 2 + 1) * 512],   \
      16, 0, 0);                                                               \
    kOff0 += TKF * ICH; kOff1 += TKF * ICH;                                    \
  }

#define QKNEXT(NXT, AOUT)                                                      \
  {                                                                            \
    AOUT = (fx16)(0.0f);                                                       \
    _Pragma("unroll")                                                          \
    for (int cs = 0; cs < 8; ++cs) {                                           \
      const h8v aK = *(const h8v*)&Ks[NXT][qlane * 128 + ((2 * cs + g) ^ swz) * 8]; \
      AOUT = __builtin_amdgcn_mfma_f32_32x32x16_f16(aK, qf[cs], AOUT, 0, 0, 0); \
    }                                                                          \
  }

#define SOFTPV(AIN, CUR)                                                       \
  {                                                                            \
    float z0 = fmaxf(AIN[0], AIN[1]),   z1 = fmaxf(AIN[2], AIN[3]);            \
    float z2 = fmaxf(AIN[4], AIN[5]),   z3 = fmaxf(AIN[6], AIN[7]);            \
    float z4 = fmaxf(AIN[8], AIN[9]),   z5 = fmaxf(AIN[10], AIN[11]);          \
    float z6 = fmaxf(AIN[12], AIN[13]), z7 = fmaxf(AIN[14], AIN[15]);          \
    z0 = fmaxf(z0, z1); z2 = fmaxf(z2, z3); z4 = fmaxf(z4, z5); z6 = fmaxf(z6, z7); \
    float mx = fmaxf(fmaxf(z0, z2), fmaxf(z4, z6));                            \
    mx = fmaxf(mx, __shfl_xor(mx, 32));                                        \
    m_true = fmaxf(m_true, mx);                                                \
    const bool fold = __any(mx > m_run + SLACK);                               \
    const float mn = fold ? fmaxf(m_run, mx) : m_run;                          \
    float lsum = 0.0f;                                                         \
    unsigned int pk[4][2];                                                     \
    _Pragma("unroll")                                                          \
    for (int u = 0; u < 4; ++u) {                                              \
      const float p0 = exp2f(AIN[4 * u + 0] - mn);                             \
      const float p1 = exp2f(AIN[4 * u + 1] - mn);                             \
      const float p2 = exp2f(AIN[4 * u + 2] - mn);                             \
      const float p3 = exp2f(AIN[4 * u + 3] - mn);                             \
      lsum += (p0 + p1) + (p2 + p3);                                           \
      pk[u][0] = pkh(p0, p1); pk[u][1] = pkh(p2, p3);                          \
    }                                                                          \
    lsum += __shfl_xor(lsum, 32);                                              \
    if (fold) {                                                                \
      const float alpha = exp2f(m_run - mn);                                   \
      l_run = l_run * alpha + lsum; m_run = mn;                                \
      _Pragma("unroll")                                                        \
      for (int mt = 0; mt < 4; ++mt)                                           \
        _Pragma("unroll")                                                      \
        for (int r = 0; r < 16; ++r) accO[mt][r] *= alpha;                     \
    } else { l_run += lsum; }                                                  \
    _Pragma("unroll")                                                          \
    for (int s = 0; s < 2; ++s) {                                              \
      const unsigned int s0 = pk[2 * s + (g ^ 1)][0];                          \
      const unsigned int s1 = pk[2 * s + (g ^ 1)][1];                          \
      const unsigned int t0 = __shfl_xor(s0, 32);                              \
      const unsigned int t1 = __shfl_xor(s1, 32);                              \
      union { unsigned int u[4]; h8v v; } bP;                                  \
      bP.u[0] = g ? t0 : pk[2 * s][0];                                         \
      bP.u[1] = g ? t1 : pk[2 * s][1];                                         \
      bP.u[2] = g ? pk[2 * s + 1][0] : t0;                                     \
      bP.u[3] = g ? pk[2 * s + 1][1] : t1;                                     \
      _Pragma("unroll")                                                        \
      for (int mt = 0; mt < 4; ++mt) {                                         \
        const int dr_ = 32 * mt + qlane;                                       \
        union { unsigned int u[4]; h8v v; } aV;                                \
        const uint2 lo = *(const uint2*)&Vs[CUR][dr_ * 36 + (2 * s + g) * 8];  \
        const uint2 hi = *(const uint2*)&Vs[CUR][dr_ * 36 + (2 * s + g) * 8 + 4]; \
        aV.u[0] = lo.x; aV.u[1] = lo.y; aV.u[2] = hi.x; aV.u[3] = hi.y;        \
        accO[mt] = __builtin_amdgcn_mfma_f32_32x32x16_f16(aV.v, bP.v, accO[mt], 0, 0, 0); \
      }                                                                        \
    }                                                                          \
  }

#define FBODY(T, CUR, NXT, STG, AIN, AOUT)                                     \
  {                                                                            \
    const bool pre_ = ((T) + 2 < NITK);                                        \
    uint4 sv0_, sv1_;                                                          \
    if (pre_) {                                                                \
      STAGEK(STG);                                                             \
      const int toff_ = ((T) + 2) * TKF;                                       \
      sv0_ = *(const uint4*)&Vsp[toff_];                                       \
      sv1_ = *(const uint4*)&Vsp[toff_ + 8];                                   \
    }                                                                          \
    QKNEXT(NXT, AOUT);                                                         \
    SOFTPV(AIN, CUR);                                                          \
    if (pre_) {                                                                \
      *(uint2*)&Vs[STG][vd]      = make_uint2(sv0_.x, sv0_.y);                 \
      *(uint2*)&Vs[STG][vd + 4]  = make_uint2(sv0_.z, sv0_.w);                 \
      *(uint2*)&Vs[STG][vd + 8]  = make_uint2(sv1_.x, sv1_.y);                 \
      *(uint2*)&Vs[STG][vd + 12] = make_uint2(sv1_.z, sv1_.w);                 \
    }                                                                          \
    __syncthreads();                                                           \
  }

__global__ __launch_bounds__(256, 3)
void flash9(const unsigned short* __restrict__ Qg,
            const unsigned short* __restrict__ Kg,
            const unsigned short* __restrict__ Vtg,
            unsigned short* __restrict__ Opart,
            float* __restrict__ Mpart,
            float* __restrict__ Lpart) {
  __shared__ unsigned short Ks[3][TKF * 128];   // 8 KB per buf, swizzled image
  __shared__ unsigned short Vs[3][128 * 36];    // 9 KB per buf, pad-36

  // XCD-slab swizzle: flat id f -> xcd = f&7 hosts slabs {2*xcd, 2*xcd+1}.
  const int f   = blockIdx.x;
  const int xcd = f & 7, j = f >> 3;            // j in [0,98)
  const int hi  = (j >= NITK) ? 1 : 0;
  const int slab = xcd * 2 + hi;                // [0,16)
  const int itile = j - hi * NITK;              // [0,49)
  const int b   = slab >> 2;
  const int spl = slab & 3;
  const int n0  = itile * 128;
  const int kb  = spl * KLEN;

  const int tid = threadIdx.x;
  const int lane = tid & 63, wv = tid >> 6;
  const int qlane = lane & 31, g = lane >> 5;
  const int swz = qlane & 15;

  h8v qf[8];
  {
    const size_t qbase = ((size_t)b * NPOS + n0 + 32 * wv + qlane) * ICH;
    #pragma unroll
    for (int cs = 0; cs < 8; ++cs)
      qf[cs] = *(const h8v*)&Qg[qbase + cs * 16 + g * 8];
  }

  // K staging source offsets (pre-swizzled so linear LDS dest carries the
  // flash5 image: row kr, slot s holds source column s^(kr&15)).
  unsigned kOff0, kOff1;
  {
    const unsigned uoff0 = (unsigned)(wv * 2 + 0) * 512 + (unsigned)lane * 8;
    const unsigned uoff1 = (unsigned)(wv * 2 + 1) * 512 + (unsigned)lane * 8;
    const unsigned kr0 = uoff0 >> 7, ks0 = (uoff0 >> 3) & 15;
    const unsigned kr1 = uoff1 >> 7, ks1 = (uoff1 >> 3) & 15;
    kOff0 = (unsigned)(b * NPOS + kb + kr0) * ICH + (ks0 ^ (kr0 & 15)) * 8;
    kOff1 = (unsigned)(b * NPOS + kb + kr1) * ICH + (ks1 ^ (kr1 & 15)) * 8;
  }
  // V staging: dr = tid>>1 (row), cvA = 2*(tid&1); each thread carries the
  // two 16B granules (cvA, cvA+1) of its row per tile.
  const int dr  = tid >> 1;
  const int cvA = 2 * (tid & 1);
  const unsigned short* Vsp = Vtg + ((size_t)b * ICH + dr) * NPOS + kb + cvA * 8;
  const int vd = dr * 36 + cvA * 8;

  // ---- prologue: tiles 0,1 -> bufs 0,1; then S(0) ----
  STAGEK(0);
  STAGEK(1);
  {
    const uint4 a0 = *(const uint4*)&Vsp[0];
    const uint4 a1 = *(const uint4*)&Vsp[8];
    const uint4 b0 = *(const uint4*)&Vsp[TKF];
    const uint4 b1 = *(const uint4*)&Vsp[TKF + 8];
    *(uint2*)&Vs[0][vd]      = make_uint2(a0.x, a0.y);
    *(uint2*)&Vs[0][vd + 4]  = make_uint2(a0.z, a0.w);
    *(uint2*)&Vs[0][vd + 8]  = make_uint2(a1.x, a1.y);
    *(uint2*)&Vs[0][vd + 12] = make_uint2(a1.z, a1.w);
    *(uint2*)&Vs[1][vd]      = make_uint2(b0.x, b0.y);
    *(uint2*)&Vs[1][vd + 4]  = make_uint2(b0.z, b0.w);
    *(uint2*)&Vs[1][vd + 8]  = make_uint2(b1.x, b1.y);
    *(uint2*)&Vs[1][vd + 12] = make_uint2(b1.z, b1.w);
  }
  __syncthreads();

  float m_run = -1e30f, m_true = -1e30f, l_run = 0.0f;
  fx16 accO[4];
  #pragma unroll
  for (int mt = 0; mt < 4; ++mt) accO[mt] = (fx16)(0.0f);

  fx16 accSA, accSB;
  QKNEXT(0, accSA);   // S(0)

  // ---- 48 steady bodies: softmax(t)+PV(t) overlap QK(t+1). 48 = 6*8 ----
  for (int tt = 0; tt < NITK - 1; tt += 6) {
    FBODY(tt + 0, 0, 1, 2, accSA, accSB)
    FBODY(tt + 1, 1, 2, 0, accSB, accSA)
    FBODY(tt + 2, 2, 0, 1, accSA, accSB)
    FBODY(tt + 3, 0, 1, 2, accSB, accSA)
    FBODY(tt + 4, 1, 2, 0, accSA, accSB)
    FBODY(tt + 5, 2, 0, 1, accSB, accSA)
  }

  // ---- epilogue: tile 48 (even -> AIN = accSA; V in buf 0) ----
  SOFTPV(accSA, 0)

  // renormalize to true max, store f16 partial O + (m,l)
  const float scale = exp2f(m_run - m_true);
  const int ncol = n0 + 32 * wv + qlane;
  const size_t obase = (size_t)(b * KSPL + spl) * ICH * NPOS;
  #pragma unroll
  for (int mt = 0; mt < 4; ++mt)
    #pragma unroll
    for (int r = 0; r < 16; ++r) {
      const int d = 32 * mt + (r & 3) + 8 * (r >> 2) + 4 * g;
      Opart[obase + (size_t)d * NPOS + ncol] = f2h(accO[mt][r] * scale);
    }
  if (g == 0) {
    Mpart[(size_t)(b * KSPL + spl) * NPOS + ncol] = m_true;
    Lpart[(size_t)(b * KSPL + spl) * NPOS + ncol] = l_run * scale;
  }
}

// ---------------------------------------------------------------------------
// merge (2n per thread): Y^T[b][d][n] = sum_s 2^{m_s-M} O_s / sum_s 2^{m_s-M} l_s
// ---------------------------------------------------------------------------
__global__ __launch_bounds__(256, 2)
void merge_kernel(const unsigned short* __restrict__ Opart,
                  const float* __restrict__ Mpart,
                  const float* __restrict__ Lpart,
                  float* __restrict__ Yt) {
  const int idx = (blockIdx.x * 256 + threadIdx.x) * 2;   // 0 .. B*N-1 step 2
  const int b = idx / NPOS, n = idx % NPOS;
  float m[KSPL][2], l[KSPL][2], M0 = -1e30f, M1 = -1e30f;
  #pragma unroll
  for (int s = 0; s < KSPL; ++s) {
    const size_t base = (size_t)(b * KSPL + s) * NPOS + n;
    m[s][0] = Mpart[base]; m[s][1] = Mpart[base + 1];
    l[s][0] = Lpart[base]; l[s][1] = Lpart[base + 1];
    M0 = fmaxf(M0, m[s][0]); M1 = fmaxf(M1, m[s][1]);
  }
  float w[KSPL][2], lt0 = 0.0f, lt1 = 0.0f;
  #pragma unroll
  for (int s = 0; s < KSPL; ++s) {
    w[s][0] = exp2f(m[s][0] - M0); lt0 += w[s][0] * l[s][0];
    w[s][1] = exp2f(m[s][1] - M1); lt1 += w[s][1] * l[s][1];
  }
  const float inv0 = 1.0f / lt0, inv1 = 1.0f / lt1;
  for (int d = 0; d < ICH; ++d) {
    float a0 = 0.0f, a1 = 0.0f;
    #pragma unroll
    for (int s = 0; s < KSPL; ++s) {
      const unsigned int u = *(const unsigned int*)
        &Opart[((size_t)(b * KSPL + s) * ICH + d) * NPOS + n];
      a0 += w[s][0] * (float)__builtin_bit_cast(_Float16, (unsigned short)(u & 0xffff));
      a1 += w[s][1] * (float)__builtin_bit_cast(_Float16, (unsigned short)(u >> 16));
    }
    float2 o; o.x = a0 * inv0; o.y = a1 * inv1;
    *(float2*)&Yt[((size_t)b * ICH + d) * NPOS + n] = o;
  }
}

// ---------------------------------------------------------------------------
// zres: out[b][c][n] = sum_ic Wz[c][ic]*Y^T[b][ic][n] + x. 128x128 block,
// 8x8 thread tile via wave quadrants (both LDS operand reads <=2-way).
// ---------------------------------------------------------------------------
__global__ __launch_bounds__(256, 2)
void zres_kernel(const float* __restrict__ x,
                 const float* __restrict__ Wz,
                 const float* __restrict__ Yt,
                 float* __restrict__ out) {
  const int n0 = blockIdx.x * 128;
  const int c0 = blockIdx.y * 128;
  const int b  = blockIdx.z;
  __shared__ float Yts[16][128];   // [k(ic)][n]
  __shared__ float Wzt[16][128];   // [k][c]
  const int tid = threadIdx.x;
  const int lane = tid & 63, wv = tid >> 6;
  const int tn = lane & 7, tc = lane >> 3;           // 8x8 within wave
  const int nb = (wv & 1) * 64 + tn * 8;             // n offset in block
  const int cb = (wv >> 1) * 64 + tc * 8;            // c offset in block
  float acc[8][8] = {};                              // [c_i][n_j]

  for (int ic0 = 0; ic0 < ICH; ic0 += 16) {
    {
      const int nn = tid & 127, kh = tid >> 7;
      #pragma unroll
      for (int q = 0; q < 8; ++q) {
        const int kk = kh + q * 2;
        Yts[kk][nn] = Yt[((size_t)b * ICH + ic0 + kk) * NPOS + n0 + nn];
      }
      const int wk = tid & 15, wo = tid >> 4;
      #pragma unroll
      for (int q = 0; q < 8; ++q) {
        const int cc = wo + q * 16;
        Wzt[wk][cc] = Wz[(size_t)(c0 + cc) * ICH + ic0 + wk];
      }
    }
    __syncthreads();
    #pragma unroll
    for (int kk = 0; kk < 16; ++kk) {
      const float4 a0 = *(const float4*)&Wzt[kk][cb];
      const float4 a1 = *(const float4*)&Wzt[kk][cb + 4];
      const float4 b0 = *(const float4*)&Yts[kk][nb];
      const float4 b1 = *(const float4*)&Yts[kk][nb + 4];
      const float a_[8] = {a0.x, a0.y, a0.z, a0.w, a1.x, a1.y, a1.z, a1.w};
      const float b_[8] = {b0.x, b0.y, b0.z, b0.w, b1.x, b1.y, b1.z, b1.w};
      #pragma unroll
      for (int i = 0; i < 8; ++i)
        #pragma unroll
        for (int j = 0; j < 8; ++j) acc[i][j] += a_[i] * b_[j];
    }
    __syncthreads();
  }
  #pragma unroll
  for (int i = 0; i < 8; ++i) {
    const size_t base = ((size_t)(b * CCH + c0 + cb + i)) * NPOS + n0 + nb;
    const float4 x0 = *(const float4*)&x[base];
    const float4 x1 = *(const float4*)&x[base + 4];
    float4 v0, v1;
    v0.x = acc[i][0] + x0.x; v0.y = acc[i][1] + x0.y;
    v0.z = acc[i][2] + x0.z; v0.w = acc[i][3] + x0.w;
    v1.x = acc[i][4] + x1.x; v1.y = acc[i][5] + x1.y;
    v1.z = acc[i][6] + x1.z; v1.w = acc[i][7] + x1.w;
    *(float4*)&out[base]     = v0;
    *(float4*)&out[base + 4] = v1;
  }
}

// ---------------------------------------------------------------------------
extern "C" void kernel_launch(void* const* d_in, const int* in_sizes, int n_in,
                              void* d_out, int out_size, void* d_ws, size_t ws_size,
                              hipStream_t stream) {
  const float* x      = (const float*)d_in[0];
  const float* Wg     = (const float*)d_in[1];
  const float* Wtheta = (const float*)d_in[2];
  const float* Wphi   = (const float*)d_in[3];
  const float* Wz     = (const float*)d_in[4];
  float* out = (float*)d_out;

  unsigned short* Qg    = (unsigned short*)d_ws;
  unsigned short* Kg    = Qg + BNIC;
  unsigned short* Vtg   = Kg + BNIC;
  unsigned short* Opart = Vtg + BNIC;                    // KSPL*BNIC ushorts
  float* Mpart = (float*)(Opart + (size_t)KSPL * BNIC);  // KSPL*B*N floats
  float* Lpart = Mpart + (size_t)KSPL * BB * NPOS;       // KSPL*B*N floats
  float* Yt    = (float*)Qg;                             // overlay after flash9

  proj_qkv<<<dim3(NPOS / 64, BB), 256, 0, stream>>>(x, Wtheta, Wphi, Wg, Qg, Kg, Vtg);
  flash9  <<<dim3(BB * KSPL * NITK), 256, 0, stream>>>(Qg, Kg, Vtg, Opart, Mpart, Lpart);
  merge_kernel<<<dim3(BB * NPOS / 512), 256, 0, stream>>>(Opart, Mpart, Lpart, Yt);
  zres_kernel<<<dim3(NPOS / 128, CCH / 128, BB), 256, 0, stream>>>(x, Wz, Yt, out);
}

// Round 5
// 361.216 us; speedup vs baseline: 1.3511x; 1.3511x over previous
//
#include <hip/hip_runtime.h>
#include <cstdint>

// SpacetimeNonLocalBlock: B=4, C=256, T*H*W=N=6272, IC=128.
// R12: consolidation. flash10 = EXACT flash5 body (R0's best, 186.9us:
// reg-staged K/V prefetch, Ks[2] 4-bit-swz, Vs[2][128x36] padded, single
// __syncthreads/iter) + two isolated proven wins: (1) flat-grid XCD-slab
// decode (flash7/8 evidence: FETCH 66->15-25MB; kernel is latency-bound on
// the per-iter vmcnt(0) drain, so L2-hit (~200cy) vs HBM (~900cy) shortens
// the dominant stall), (2) tree fmax (serial chain 15->4+1 deep).
// R8-R11 lessons (all regressed, do not revisit): gload_lds+launch_bounds(4)
// -> bank conflicts/L2 thrash; depth-2 vmcnt pipeline -> +56 VGPR; S-ahead
// V-reg staging live across softmax -> scratch spill (WRITE 184MB).
// merge_kernel: grid 49 -> 49x4 (d-chunks of 32); was 19% CU util for 38MB.

#define BB   4
#define CCH  256
#define NPOS 6272
#define ICH  128
#define BNIC ((size_t)BB * NPOS * ICH)
#define KSPL 4
#define KLEN (NPOS / KSPL)   // 1568
#define TKF  32
#define NITK (KLEN / TKF)    // 49
#define SLACK 12.0f

typedef __attribute__((ext_vector_type(8)))  _Float16 h8v;  // 8 f16 MFMA frag
typedef __attribute__((ext_vector_type(16))) float fx16;    // 32x32 acc

__device__ __forceinline__ unsigned short f2h(float f) {
  _Float16 h = (_Float16)f;
  return __builtin_bit_cast(unsigned short, h);
}
__device__ __forceinline__ unsigned int pkh(float lo, float hi) {
  return __builtin_bit_cast(unsigned int, __builtin_amdgcn_cvt_pkrtz(lo, hi));
}

// ---------------------------------------------------------------------------
// proj_qkv: fused Q/K/V projections. grid (N/64, B); block 256.
// Q,K -> [b][n][128] f16 (Q pre-scaled log2e); V -> V^T [b][128][N] f16.
// LDS 30.5 KB: Xt[16][68] + Wt[6][16][68]. Inner: 1 av + 6 bv b128 per kk.
// ---------------------------------------------------------------------------
__global__ __launch_bounds__(256, 1)
void proj_qkv(const float* __restrict__ x,
              const float* __restrict__ Wtheta,
              const float* __restrict__ Wphi,
              const float* __restrict__ Wg,
              unsigned short* __restrict__ Qg,
              unsigned short* __restrict__ Kg,
              unsigned short* __restrict__ Vtg) {
  const int n0 = blockIdx.x * 64;
  const int b  = blockIdx.y;
  __shared__ float Xt[16][68];      // [k][n]
  __shared__ float Wt[6][16][68];   // [tile][k][o]
  const int tid = threadIdx.x;
  const int tx = tid & 15, ty = tid >> 4;
  float acc[6][4][4] = {};          // [tile][n_i][o_j]
  const float* Ws[3] = {Wtheta, Wphi, Wg};

  for (int c0 = 0; c0 < CCH; c0 += 16) {
    {
      const int nn = tid & 63, k4 = tid >> 6;
      #pragma unroll
      for (int q = 0; q < 4; ++q) {
        const int kk = k4 + q * 4;
        Xt[kk][nn] = x[((size_t)(b * CCH + c0 + kk)) * NPOS + n0 + nn];
      }
      const int wk = tid & 15, wo = tid >> 4;
      #pragma unroll
      for (int w = 0; w < 6; ++w) {
        const float* W = Ws[w >> 1];
        const int o_half = (w & 1) * 64;
        #pragma unroll
        for (int q = 0; q < 4; ++q) {
          const int oo = wo + q * 16;
          Wt[w][wk][oo] = W[(size_t)(o_half + oo) * CCH + c0 + wk];
        }
      }
    }
    __syncthreads();
    #pragma unroll
    for (int kk = 0; kk < 16; ++kk) {
      const float4 av = *(const float4*)&Xt[kk][ty * 4];
      const float a_[4] = {av.x, av.y, av.z, av.w};
      #pragma unroll
      for (int w = 0; w < 6; ++w) {
        const float4 bv = *(const float4*)&Wt[w][kk][tx * 4];
        const float b_[4] = {bv.x, bv.y, bv.z, bv.w};
        #pragma unroll
        for (int i = 0; i < 4; ++i)
          #pragma unroll
          for (int j = 0; j < 4; ++j) acc[w][i][j] += a_[i] * b_[j];
      }
    }
    __syncthreads();
  }

  const float LOG2E = 1.4426950408889634f;
  // Q (tiles 0,1) and K (tiles 2,3): [n][o] rows
  #pragma unroll
  for (int w = 0; w < 4; ++w) {
    const int o_half = (w & 1) * 64;
    unsigned short* Out = (w < 2) ? Qg : Kg;
    const float scl = (w < 2) ? LOG2E : 1.0f;
    #pragma unroll
    for (int i = 0; i < 4; ++i) {
      ushort4 v;
      v.x = f2h(acc[w][i][0] * scl); v.y = f2h(acc[w][i][1] * scl);
      v.z = f2h(acc[w][i][2] * scl); v.w = f2h(acc[w][i][3] * scl);
      *(ushort4*)&Out[((size_t)b * NPOS + n0 + ty * 4 + i) * ICH + o_half + tx * 4] = v;
    }
  }
  // V (tiles 4,5): V^T[o][n] — transpose in-register (i<->j roles)
  #pragma unroll
  for (int w = 4; w < 6; ++w) {
    const int o_half = (w & 1) * 64;
    #pragma unroll
    for (int j = 0; j < 4; ++j) {
      const int o = o_half + tx * 4 + j;
      ushort4 v;
      v.x = f2h(acc[w][0][j]); v.y = f2h(acc[w][1][j]);
      v.z = f2h(acc[w][2][j]); v.w = f2h(acc[w][3][j]);
      *(ushort4*)&Vtg[((size_t)b * ICH + o) * NPOS + n0 + ty * 4] = v;
    }
  }
}

// ---------------------------------------------------------------------------
// flash10: EXACT flash5 body; flat grid 784 decoded so XCD k (=f&7) hosts
// K/V slabs {2k,2k+1} (1.6 MB/L2, 49 sharing blocks co-located on one XCD).
// 4 waves, q=32/wave, TK=32, slack-fold softmax, tree max.
// LDS 34 KB: Ks[2][32x128] 4-bit swz, Vs[2][128x36].
// ---------------------------------------------------------------------------
__global__ __launch_bounds__(256, 2)
void flash10(const unsigned short* __restrict__ Qg,
             const unsigned short* __restrict__ Kg,
             const unsigned short* __restrict__ Vtg,
             unsigned short* __restrict__ Opart,
             float* __restrict__ Mpart,
             float* __restrict__ Lpart) {
  __shared__ unsigned short Ks[2][TKF * 128];
  __shared__ unsigned short Vs[2][128 * 36];

  // XCD-slab decode: f&7 = xcd hosts slabs {2*xcd, 2*xcd+1}.
  const int f   = blockIdx.x;
  const int xcd = f & 7, j = f >> 3;            // j in [0,98)
  const int hi  = (j >= NITK) ? 1 : 0;
  const int slab = xcd * 2 + hi;                // [0,16)
  const int itile = j - hi * NITK;              // [0,49)
  const int b   = slab >> 2;
  const int spl = slab & 3;
  const int n0  = itile * 128;
  const int kb  = spl * KLEN;

  const int tid = threadIdx.x;
  const int lane = tid & 63, wv = tid >> 6;
  const int qlane = lane & 31, g = lane >> 5;
  const int swz = qlane & 15;

  h8v qf[8];
  {
    const size_t qbase = ((size_t)b * NPOS + n0 + 32 * wv + qlane) * ICH;
    #pragma unroll
    for (int cs = 0; cs < 8; ++cs)
      qf[cs] = *(const h8v*)&Qg[qbase + cs * 16 + g * 8];
  }

  {
    #pragma unroll
    for (int i = 0; i < 2; ++i) {
      const int kr = (tid >> 4) + i * 16, c = tid & 15;
      const uint4 v = *(const uint4*)&Kg[((size_t)b * NPOS + kb + kr) * ICH + c * 8];
      *(uint4*)&Ks[0][kr * 128 + (c ^ (kr & 15)) * 8] = v;
      const int idx = tid * 2 + i, dr = idx >> 2, cv = idx & 3;
      const uint4 w = *(const uint4*)&Vtg[((size_t)b * ICH + dr) * NPOS + kb + cv * 8];
      *(uint2*)&Vs[0][dr * 36 + cv * 8]     = make_uint2(w.x, w.y);
      *(uint2*)&Vs[0][dr * 36 + cv * 8 + 4] = make_uint2(w.z, w.w);
    }
  }
  __syncthreads();

  float m_run = -1e30f, m_true = -1e30f, l_run = 0.0f;
  fx16 accO[4];
  #pragma unroll
  for (int mt = 0; mt < 4; ++mt) accO[mt] = (fx16)(0.0f);

  uint4 stgK[2], stgV[2];

  for (int it = 0; it < NITK; ++it) {
    const int cur = it & 1;
    const bool pre = (it + 1 < NITK);
    if (pre) {
      const int k0n = kb + (it + 1) * TKF;
      #pragma unroll
      for (int i = 0; i < 2; ++i) {
        const int kr = (tid >> 4) + i * 16;
        stgK[i] = *(const uint4*)&Kg[((size_t)b * NPOS + k0n + kr) * ICH + (tid & 15) * 8];
        const int idx = tid * 2 + i, dr = idx >> 2, cv = idx & 3;
        stgV[i] = *(const uint4*)&Vtg[((size_t)b * ICH + dr) * NPOS + k0n + cv * 8];
      }
    }

    // ---- S^T = K . Q^T ----
    fx16 accS = (fx16)(0.0f);
    #pragma unroll
    for (int cs = 0; cs < 8; ++cs) {
      const h8v aK = *(const h8v*)&Ks[cur][qlane * 128 + ((2 * cs + g) ^ swz) * 8];
      accS = __builtin_amdgcn_mfma_f32_32x32x16_f16(aK, qf[cs], accS, 0, 0, 0);
    }

    // ---- slack-fold online softmax (log2 domain), tree max ----
    float a0 = fmaxf(accS[0], accS[1]),   a1 = fmaxf(accS[2], accS[3]);
    float a2 = fmaxf(accS[4], accS[5]),   a3 = fmaxf(accS[6], accS[7]);
    float a4 = fmaxf(accS[8], accS[9]),   a5 = fmaxf(accS[10], accS[11]);
    float a6 = fmaxf(accS[12], accS[13]), a7 = fmaxf(accS[14], accS[15]);
    a0 = fmaxf(a0, a1); a2 = fmaxf(a2, a3); a4 = fmaxf(a4, a5); a6 = fmaxf(a6, a7);
    float mx = fmaxf(fmaxf(a0, a2), fmaxf(a4, a6));
    mx = fmaxf(mx, __shfl_xor(mx, 32));
    m_true = fmaxf(m_true, mx);
    const bool fold = __any(mx > m_run + SLACK);
    const float mn = fold ? fmaxf(m_run, mx) : m_run;
    float lsum = 0.0f;
    unsigned int pk[4][2];
    #pragma unroll
    for (int u = 0; u < 4; ++u) {
      const float p0 = exp2f(accS[4 * u + 0] - mn);
      const float p1 = exp2f(accS[4 * u + 1] - mn);
      const float p2 = exp2f(accS[4 * u + 2] - mn);
      const float p3 = exp2f(accS[4 * u + 3] - mn);
      lsum += (p0 + p1) + (p2 + p3);
      pk[u][0] = pkh(p0, p1);
      pk[u][1] = pkh(p2, p3);
    }
    lsum += __shfl_xor(lsum, 32);
    if (fold) {
      const float alpha = exp2f(m_run - mn);
      l_run = l_run * alpha + lsum;
      m_run = mn;
      #pragma unroll
      for (int mt = 0; mt < 4; ++mt)
        #pragma unroll
        for (int r = 0; r < 16; ++r) accO[mt][r] *= alpha;
    } else {
      l_run += lsum;
    }

    // ---- PV: O^T += V^T . P^T ----
    #pragma unroll
    for (int s = 0; s < 2; ++s) {
      const unsigned int s0 = pk[2 * s + (g ^ 1)][0];
      const unsigned int s1 = pk[2 * s + (g ^ 1)][1];
      const unsigned int t0 = __shfl_xor(s0, 32);
      const unsigned int t1 = __shfl_xor(s1, 32);
      union { unsigned int u[4]; h8v v; } bP;
      bP.u[0] = g ? t0 : pk[2 * s][0];
      bP.u[1] = g ? t1 : pk[2 * s][1];
      bP.u[2] = g ? pk[2 * s + 1][0] : t0;
      bP.u[3] = g ? pk[2 * s + 1][1] : t1;
      #pragma unroll
      for (int mt = 0; mt < 4; ++mt) {
        const int dr = 32 * mt + qlane;
        union { unsigned int u[4]; h8v v; } aV;
        const uint2 lo = *(const uint2*)&Vs[cur][dr * 36 + (2 * s + g) * 8];
        const uint2 hi = *(const uint2*)&Vs[cur][dr * 36 + (2 * s + g) * 8 + 4];
        aV.u[0] = lo.x; aV.u[1] = lo.y; aV.u[2] = hi.x; aV.u[3] = hi.y;
        accO[mt] = __builtin_amdgcn_mfma_f32_32x32x16_f16(aV.v, bP.v, accO[mt], 0, 0, 0);
      }
    }

    if (pre) {
      const int nb = cur ^ 1;
      #pragma unroll
      for (int i = 0; i < 2; ++i) {
        const int kr = (tid >> 4) + i * 16;
        *(uint4*)&Ks[nb][kr * 128 + ((tid & 15) ^ (kr & 15)) * 8] = stgK[i];
        const int idx = tid * 2 + i, dr = idx >> 2, cv = idx & 3;
        *(uint2*)&Vs[nb][dr * 36 + cv * 8]     = make_uint2(stgV[i].x, stgV[i].y);
        *(uint2*)&Vs[nb][dr * 36 + cv * 8 + 4] = make_uint2(stgV[i].z, stgV[i].w);
      }
    }
    __syncthreads();
  }

  // epilogue: renormalize to true max, store f16 partial O + (m,l)
  const float scale = exp2f(m_run - m_true);
  const int ncol = n0 + 32 * wv + qlane;
  const size_t obase = (size_t)(b * KSPL + spl) * ICH * NPOS;
  #pragma unroll
  for (int mt = 0; mt < 4; ++mt)
    #pragma unroll
    for (int r = 0; r < 16; ++r) {
      const int d = 32 * mt + (r & 3) + 8 * (r >> 2) + 4 * g;
      Opart[obase + (size_t)d * NPOS + ncol] = f2h(accO[mt][r] * scale);
    }
  if (g == 0) {
    Mpart[(size_t)(b * KSPL + spl) * NPOS + ncol] = m_true;
    Lpart[(size_t)(b * KSPL + spl) * NPOS + ncol] = l_run * scale;
  }
}

// ---------------------------------------------------------------------------
// merge: Y^T[b][d][n] = sum_s 2^{m_s-M} O_s / sum_s 2^{m_s-M} l_s.
// grid (49, 4): x covers 512 n (2/thread), y covers d-chunk of 32 rows.
// Weight recompute per chunk is 16 loads/thread — negligible vs 4x CU util.
// ---------------------------------------------------------------------------
__global__ __launch_bounds__(256, 2)
void merge_kernel(const unsigned short* __restrict__ Opart,
                  const float* __restrict__ Mpart,
                  const float* __restrict__ Lpart,
                  float* __restrict__ Yt) {
  const int idx = (blockIdx.x * 256 + threadIdx.x) * 2;   // 0 .. B*N-1 step 2
  const int d0  = blockIdx.y * 32;
  const int b = idx / NPOS, n = idx % NPOS;
  float m[KSPL][2], l[KSPL][2], M0 = -1e30f, M1 = -1e30f;
  #pragma unroll
  for (int s = 0; s < KSPL; ++s) {
    const size_t base = (size_t)(b * KSPL + s) * NPOS + n;
    m[s][0] = Mpart[base]; m[s][1] = Mpart[base + 1];
    l[s][0] = Lpart[base]; l[s][1] = Lpart[base + 1];
    M0 = fmaxf(M0, m[s][0]); M1 = fmaxf(M1, m[s][1]);
  }
  float w[KSPL][2], lt0 = 0.0f, lt1 = 0.0f;
  #pragma unroll
  for (int s = 0; s < KSPL; ++s) {
    w[s][0] = exp2f(m[s][0] - M0); lt0 += w[s][0] * l[s][0];
    w[s][1] = exp2f(m[s][1] - M1); lt1 += w[s][1] * l[s][1];
  }
  const float inv0 = 1.0f / lt0, inv1 = 1.0f / lt1;
  for (int d = d0; d < d0 + 32; ++d) {
    float a0 = 0.0f, a1 = 0.0f;
    #pragma unroll
    for (int s = 0; s < KSPL; ++s) {
      const unsigned int u = *(const unsigned int*)
        &Opart[((size_t)(b * KSPL + s) * ICH + d) * NPOS + n];
      a0 += w[s][0] * (float)__builtin_bit_cast(_Float16, (unsigned short)(u & 0xffff));
      a1 += w[s][1] * (float)__builtin_bit_cast(_Float16, (unsigned short)(u >> 16));
    }
    float2 o; o.x = a0 * inv0; o.y = a1 * inv1;
    *(float2*)&Yt[((size_t)b * ICH + d) * NPOS + n] = o;
  }
}

// ---------------------------------------------------------------------------
// zres: out[b][c][n] = sum_ic Wz[c][ic]*Y^T[b][ic][n] + x. 128x128 block,
// 8x8 thread tile via wave quadrants (both LDS operand reads <=2-way).
// ---------------------------------------------------------------------------
__global__ __launch_bounds__(256, 2)
void zres_kernel(const float* __restrict__ x,
                 const float* __restrict__ Wz,
                 const float* __restrict__ Yt,
                 float* __restrict__ out) {
  const int n0 = blockIdx.x * 128;
  const int c0 = blockIdx.y * 128;
  const int b  = blockIdx.z;
  __shared__ float Yts[16][128];   // [k(ic)][n]
  __shared__ float Wzt[16][128];   // [k][c]
  const int tid = threadIdx.x;
  const int lane = tid & 63, wv = tid >> 6;
  const int tn = lane & 7, tc = lane >> 3;           // 8x8 within wave
  const int nb = (wv & 1) * 64 + tn * 8;             // n offset in block
  const int cb = (wv >> 1) * 64 + tc * 8;            // c offset in block
  float acc[8][8] = {};                              // [c_i][n_j]

  for (int ic0 = 0; ic0 < ICH; ic0 += 16) {
    {
      const int nn = tid & 127, kh = tid >> 7;
      #pragma unroll
      for (int q = 0; q < 8; ++q) {
        const int kk = kh + q * 2;
        Yts[kk][nn] = Yt[((size_t)b * ICH + ic0 + kk) * NPOS + n0 + nn];
      }
      const int wk = tid & 15, wo = tid >> 4;
      #pragma unroll
      for (int q = 0; q < 8; ++q) {
        const int cc = wo + q * 16;
        Wzt[wk][cc] = Wz[(size_t)(c0 + cc) * ICH + ic0 + wk];
      }
    }
    __syncthreads();
    #pragma unroll
    for (int kk = 0; kk < 16; ++kk) {
      const float4 a0 = *(const float4*)&Wzt[kk][cb];
      const float4 a1 = *(const float4*)&Wzt[kk][cb + 4];
      const float4 b0 = *(const float4*)&Yts[kk][nb];
      const float4 b1 = *(const float4*)&Yts[kk][nb + 4];
      const float a_[8] = {a0.x, a0.y, a0.z, a0.w, a1.x, a1.y, a1.z, a1.w};
      const float b_[8] = {b0.x, b0.y, b0.z, b0.w, b1.x, b1.y, b1.z, b1.w};
      #pragma unroll
      for (int i = 0; i < 8; ++i)
        #pragma unroll
        for (int j = 0; j < 8; ++j) acc[i][j] += a_[i] * b_[j];
    }
    __syncthreads();
  }
  #pragma unroll
  for (int i = 0; i < 8; ++i) {
    const size_t base = ((size_t)(b * CCH + c0 + cb + i)) * NPOS + n0 + nb;
    const float4 x0 = *(const float4*)&x[base];
    const float4 x1 = *(const float4*)&x[base + 4];
    float4 v0, v1;
    v0.x = acc[i][0] + x0.x; v0.y = acc[i][1] + x0.y;
    v0.z = acc[i][2] + x0.z; v0.w = acc[i][3] + x0.w;
    v1.x = acc[i][4] + x1.x; v1.y = acc[i][5] + x1.y;
    v1.z = acc[i][6] + x1.z; v1.w = acc[i][7] + x1.w;
    *(float4*)&out[base]     = v0;
    *(float4*)&out[base + 4] = v1;
  }
}

// ---------------------------------------------------------------------------
extern "C" void kernel_launch(void* const* d_in, const int* in_sizes, int n_in,
                              void* d_out, int out_size, void* d_ws, size_t ws_size,
                              hipStream_t stream) {
  const float* x      = (const float*)d_in[0];
  const float* Wg     = (const float*)d_in[1];
  const float* Wtheta = (const float*)d_in[2];
  const float* Wphi   = (const float*)d_in[3];
  const float* Wz     = (const float*)d_in[4];
  float* out = (float*)d_out;

  unsigned short* Qg    = (unsigned short*)d_ws;
  unsigned short* Kg    = Qg + BNIC;
  unsigned short* Vtg   = Kg + BNIC;
  unsigned short* Opart = Vtg + BNIC;                    // KSPL*BNIC ushorts
  float* Mpart = (float*)(Opart + (size_t)KSPL * BNIC);  // KSPL*B*N floats
  float* Lpart = Mpart + (size_t)KSPL * BB * NPOS;       // KSPL*B*N floats
  float* Yt    = (float*)Qg;                             // overlay after flash10

  proj_qkv<<<dim3(NPOS / 64, BB), 256, 0, stream>>>(x, Wtheta, Wphi, Wg, Qg, Kg, Vtg);
  flash10 <<<dim3(BB * KSPL * NITK), 256, 0, stream>>>(Qg, Kg, Vtg, Opart, Mpart, Lpart);
  merge_kernel<<<dim3(BB * NPOS / 512, 4), 256, 0, stream>>>(Opart, Mpart, Lpart, Yt);
  zres_kernel<<<dim3(NPOS / 128, CCH / 128, BB), 256, 0, stream>>>(x, Wz, Yt, out);
}

// Round 6
// 342.085 us; speedup vs baseline: 1.4267x; 1.0559x over previous
//
#include <hip/hip_runtime.h>
#include <cstdint>

// SpacetimeNonLocalBlock: B=4, C=256, T*H*W=N=6272, IC=128.
// R13: proj_qkv (fp32 VALU GEMM, >=31us at 157TF vector peak) replaced by
// proj_mfma: f16 hi/lo-split MFMA GEMM (Whi*xhi + Whi*xlo + Wlo*xhi, f32
// accum -> f32-faithful numerics, absmax must stay 0.03125). Weights
// pre-converted by wconv into hi/lo f16, overlaid on the Opart workspace
// region (dead until flash10 writes it). flash10/merge/zres = R12 verbatim
// (flash proven plateaued: FETCH 66->13MB with zero dur change; serial-chain
// bound at MfmaUtil 18.5). R8-R11 lessons: no gload_lds-in-flash, no deep
// pipelines, no staged data live across softmax.

#define BB   4
#define CCH  256
#define NPOS 6272
#define ICH  128
#define BNIC ((size_t)BB * NPOS * ICH)
#define KSPL 4
#define KLEN (NPOS / KSPL)   // 1568
#define TKF  32
#define NITK (KLEN / TKF)    // 49
#define SLACK 12.0f

typedef __attribute__((ext_vector_type(8)))  _Float16 h8v;  // 8 f16 MFMA frag
typedef __attribute__((ext_vector_type(16))) float fx16;    // 32x32 acc

__device__ __forceinline__ unsigned short f2h(float f) {
  _Float16 h = (_Float16)f;
  return __builtin_bit_cast(unsigned short, h);
}
__device__ __forceinline__ unsigned int pkh(float lo, float hi) {
  return __builtin_bit_cast(unsigned int, __builtin_amdgcn_cvt_pkrtz(lo, hi));
}

// ---------------------------------------------------------------------------
// wconv: [Wtheta;Wphi;Wg] (3x128x256 f32) -> Whi/Wlo f16 split. grid 96.
// ---------------------------------------------------------------------------
__global__ __launch_bounds__(256, 1)
void wconv(const float* __restrict__ Wtheta, const float* __restrict__ Wphi,
           const float* __restrict__ Wg,
           unsigned short* __restrict__ Whi, unsigned short* __restrict__ Wlo) {
  const int idx4 = (blockIdx.x * 256 + threadIdx.x) * 4;   // [0, 98304) step 4
  const int p = idx4 >> 15;                                // 0,1,2 (128*256=32768)
  const float* W = (p == 0) ? Wtheta : (p == 1) ? Wphi : Wg;
  const float4 v = *(const float4*)&W[idx4 - (p << 15)];
  const float vv[4] = {v.x, v.y, v.z, v.w};
  ushort4 h, l;
  unsigned short* hp = (unsigned short*)&h;
  unsigned short* lp = (unsigned short*)&l;
  #pragma unroll
  for (int q = 0; q < 4; ++q) {
    _Float16 hh = (_Float16)vv[q];
    hp[q] = __builtin_bit_cast(unsigned short, hh);
    lp[q] = f2h(vv[q] - (float)hh);
  }
  *(ushort4*)&Whi[idx4] = h;
  *(ushort4*)&Wlo[idx4] = l;
}

// ---------------------------------------------------------------------------
// proj_mfma: grid (N/32, B), 256 thr (4 waves). Wave wv owns o-tiles
// T = wv*3 + t (t<3): T/4 = proj (0:theta->Qg *log2e, 1:phi->Kg, 2:g->Vtg).
// x chunk [32n][16c] transpose-staged to LDS as f16 hi/lo ([32][24], 48B
// rows -> 16B-aligned b128 reads, 4-way conflict accepted). W frags direct
// from L2-resident Whi/Wlo. 3 MFMA per tile per chunk (hi*hi+hi*lo+lo*hi).
// ---------------------------------------------------------------------------
__global__ __launch_bounds__(256, 2)
void proj_mfma(const float* __restrict__ x,
               const unsigned short* __restrict__ Whi,
               const unsigned short* __restrict__ Wlo,
               unsigned short* __restrict__ Qg,
               unsigned short* __restrict__ Kg,
               unsigned short* __restrict__ Vtg) {
  __shared__ unsigned short Xhi[32][24];
  __shared__ unsigned short Xlo[32][24];
  const int n0 = blockIdx.x * 32;
  const int b  = blockIdx.y;
  const int tid = threadIdx.x;
  const int lane = tid & 63, wv = tid >> 6;
  const int ln = lane & 31, g = lane >> 5;

  fx16 acc[3];
  acc[0] = (fx16)(0.0f); acc[1] = (fx16)(0.0f); acc[2] = (fx16)(0.0f);

  // staging coords: row sn, c-pair cp (each thread carries 2 c of one n-row)
  const int sn = tid & 31, cp = (tid >> 5) * 2;
  const float* xp = x + ((size_t)b * CCH + cp) * NPOS + n0 + sn;

  float pv0 = xp[0];
  float pv1 = xp[NPOS];

  for (int c0 = 0; c0 < CCH; c0 += 16) {
    // write staged chunk (pv holds x[cp+c0], x[cp+1+c0] for row sn)
    {
      _Float16 h0 = (_Float16)pv0, h1 = (_Float16)pv1;
      ushort2 hh, ll;
      hh.x = __builtin_bit_cast(unsigned short, h0);
      hh.y = __builtin_bit_cast(unsigned short, h1);
      ll.x = f2h(pv0 - (float)h0);
      ll.y = f2h(pv1 - (float)h1);
      *(ushort2*)&Xhi[sn][cp] = hh;
      *(ushort2*)&Xlo[sn][cp] = ll;
    }
    // issue next chunk's loads early (hidden under this chunk's MFMA)
    if (c0 + 16 < CCH) {
      pv0 = xp[(size_t)(c0 + 16) * NPOS];
      pv1 = xp[(size_t)(c0 + 17) * NPOS];
    }
    __syncthreads();
    const h8v bxh = *(const h8v*)&Xhi[ln][g * 8];
    const h8v bxl = *(const h8v*)&Xlo[ln][g * 8];
    #pragma unroll
    for (int t = 0; t < 3; ++t) {
      const int T = wv * 3 + t;
      const size_t wb = ((size_t)(T * 32 + ln)) * CCH + c0 + g * 8;
      const h8v ah = *(const h8v*)&Whi[wb];
      const h8v al = *(const h8v*)&Wlo[wb];
      acc[t] = __builtin_amdgcn_mfma_f32_32x32x16_f16(ah, bxh, acc[t], 0, 0, 0);
      acc[t] = __builtin_amdgcn_mfma_f32_32x32x16_f16(ah, bxl, acc[t], 0, 0, 0);
      acc[t] = __builtin_amdgcn_mfma_f32_32x32x16_f16(al, bxh, acc[t], 0, 0, 0);
    }
    __syncthreads();
  }

  // epilogue: C[o_row][n=ln]; o_row(r) = (r&3) + 8*(r>>2) + 4*g
  const float LOG2E = 1.4426950408889634f;
  const int n = n0 + ln;
  #pragma unroll
  for (int t = 0; t < 3; ++t) {
    const int T = wv * 3 + t;
    const int p = T >> 2;
    const int ot = (T & 3) * 32;
    if (p < 2) {
      unsigned short* Out = (p == 0) ? Qg : Kg;
      const float scl = (p == 0) ? LOG2E : 1.0f;
      #pragma unroll
      for (int q = 0; q < 4; ++q) {
        ushort4 v;
        v.x = f2h(acc[t][4 * q + 0] * scl);
        v.y = f2h(acc[t][4 * q + 1] * scl);
        v.z = f2h(acc[t][4 * q + 2] * scl);
        v.w = f2h(acc[t][4 * q + 3] * scl);
        *(ushort4*)&Out[((size_t)b * NPOS + n) * ICH + ot + 8 * q + 4 * g] = v;
      }
    } else {
      #pragma unroll
      for (int r = 0; r < 16; ++r) {
        const int o = ot + (r & 3) + 8 * (r >> 2) + 4 * g;
        Vtg[((size_t)b * ICH + o) * NPOS + n] = f2h(acc[t][r]);
      }
    }
  }
}

// ---------------------------------------------------------------------------
// flash10: EXACT flash5 body; flat grid 784 decoded so XCD k (=f&7) hosts
// K/V slabs {2k,2k+1}. 4 waves, q=32/wave, TK=32, slack-fold softmax,
// tree max. LDS 34 KB: Ks[2][32x128] 4-bit swz, Vs[2][128x36].
// ---------------------------------------------------------------------------
__global__ __launch_bounds__(256, 2)
void flash10(const unsigned short* __restrict__ Qg,
             const unsigned short* __restrict__ Kg,
             const unsigned short* __restrict__ Vtg,
             unsigned short* __restrict__ Opart,
             float* __restrict__ Mpart,
             float* __restrict__ Lpart) {
  __shared__ unsigned short Ks[2][TKF * 128];
  __shared__ unsigned short Vs[2][128 * 36];

  const int f   = blockIdx.x;
  const int xcd = f & 7, j = f >> 3;            // j in [0,98)
  const int hi  = (j >= NITK) ? 1 : 0;
  const int slab = xcd * 2 + hi;                // [0,16)
  const int itile = j - hi * NITK;              // [0,49)
  const int b   = slab >> 2;
  const int spl = slab & 3;
  const int n0  = itile * 128;
  const int kb  = spl * KLEN;

  const int tid = threadIdx.x;
  const int lane = tid & 63, wv = tid >> 6;
  const int qlane = lane & 31, g = lane >> 5;
  const int swz = qlane & 15;

  h8v qf[8];
  {
    const size_t qbase = ((size_t)b * NPOS + n0 + 32 * wv + qlane) * ICH;
    #pragma unroll
    for (int cs = 0; cs < 8; ++cs)
      qf[cs] = *(const h8v*)&Qg[qbase + cs * 16 + g * 8];
  }

  {
    #pragma unroll
    for (int i = 0; i < 2; ++i) {
      const int kr = (tid >> 4) + i * 16, c = tid & 15;
      const uint4 v = *(const uint4*)&Kg[((size_t)b * NPOS + kb + kr) * ICH + c * 8];
      *(uint4*)&Ks[0][kr * 128 + (c ^ (kr & 15)) * 8] = v;
      const int idx = tid * 2 + i, dr = idx >> 2, cv = idx & 3;
      const uint4 w = *(const uint4*)&Vtg[((size_t)b * ICH + dr) * NPOS + kb + cv * 8];
      *(uint2*)&Vs[0][dr * 36 + cv * 8]     = make_uint2(w.x, w.y);
      *(uint2*)&Vs[0][dr * 36 + cv * 8 + 4] = make_uint2(w.z, w.w);
    }
  }
  __syncthreads();

  float m_run = -1e30f, m_true = -1e30f, l_run = 0.0f;
  fx16 accO[4];
  #pragma unroll
  for (int mt = 0; mt < 4; ++mt) accO[mt] = (fx16)(0.0f);

  uint4 stgK[2], stgV[2];

  for (int it = 0; it < NITK; ++it) {
    const int cur = it & 1;
    const bool pre = (it + 1 < NITK);
    if (pre) {
      const int k0n = kb + (it + 1) * TKF;
      #pragma unroll
      for (int i = 0; i < 2; ++i) {
        const int kr = (tid >> 4) + i * 16;
        stgK[i] = *(const uint4*)&Kg[((size_t)b * NPOS + k0n + kr) * ICH + (tid & 15) * 8];
        const int idx = tid * 2 + i, dr = idx >> 2, cv = idx & 3;
        stgV[i] = *(const uint4*)&Vtg[((size_t)b * ICH + dr) * NPOS + k0n + cv * 8];
      }
    }

    // ---- S^T = K . Q^T ----
    fx16 accS = (fx16)(0.0f);
    #pragma unroll
    for (int cs = 0; cs < 8; ++cs) {
      const h8v aK = *(const h8v*)&Ks[cur][qlane * 128 + ((2 * cs + g) ^ swz) * 8];
      accS = __builtin_amdgcn_mfma_f32_32x32x16_f16(aK, qf[cs], accS, 0, 0, 0);
    }

    // ---- slack-fold online softmax (log2 domain), tree max ----
    float a0 = fmaxf(accS[0], accS[1]),   a1 = fmaxf(accS[2], accS[3]);
    float a2 = fmaxf(accS[4], accS[5]),   a3 = fmaxf(accS[6], accS[7]);
    float a4 = fmaxf(accS[8], accS[9]),   a5 = fmaxf(accS[10], accS[11]);
    float a6 = fmaxf(accS[12], accS[13]), a7 = fmaxf(accS[14], accS[15]);
    a0 = fmaxf(a0, a1); a2 = fmaxf(a2, a3); a4 = fmaxf(a4, a5); a6 = fmaxf(a6, a7);
    float mx = fmaxf(fmaxf(a0, a2), fmaxf(a4, a6));
    mx = fmaxf(mx, __shfl_xor(mx, 32));
    m_true = fmaxf(m_true, mx);
    const bool fold = __any(mx > m_run + SLACK);
    const float mn = fold ? fmaxf(m_run, mx) : m_run;
    float lsum = 0.0f;
    unsigned int pk[4][2];
    #pragma unroll
    for (int u = 0; u < 4; ++u) {
      const float p0 = exp2f(accS[4 * u + 0] - mn);
      const float p1 = exp2f(accS[4 * u + 1] - mn);
      const float p2 = exp2f(accS[4 * u + 2] - mn);
      const float p3 = exp2f(accS[4 * u + 3] - mn);
      lsum += (p0 + p1) + (p2 + p3);
      pk[u][0] = pkh(p0, p1);
      pk[u][1] = pkh(p2, p3);
    }
    lsum += __shfl_xor(lsum, 32);
    if (fold) {
      const float alpha = exp2f(m_run - mn);
      l_run = l_run * alpha + lsum;
      m_run = mn;
      #pragma unroll
      for (int mt = 0; mt < 4; ++mt)
        #pragma unroll
        for (int r = 0; r < 16; ++r) accO[mt][r] *= alpha;
    } else {
      l_run += lsum;
    }

    // ---- PV: O^T += V^T . P^T ----
    #pragma unroll
    for (int s = 0; s < 2; ++s) {
      const unsigned int s0 = pk[2 * s + (g ^ 1)][0];
      const unsigned int s1 = pk[2 * s + (g ^ 1)][1];
      const unsigned int t0 = __shfl_xor(s0, 32);
      const unsigned int t1 = __shfl_xor(s1, 32);
      union { unsigned int u[4]; h8v v; } bP;
      bP.u[0] = g ? t0 : pk[2 * s][0];
      bP.u[1] = g ? t1 : pk[2 * s][1];
      bP.u[2] = g ? pk[2 * s + 1][0] : t0;
      bP.u[3] = g ? pk[2 * s + 1][1] : t1;
      #pragma unroll
      for (int mt = 0; mt < 4; ++mt) {
        const int dr = 32 * mt + qlane;
        union { unsigned int u[4]; h8v v; } aV;
        const uint2 lo = *(const uint2*)&Vs[cur][dr * 36 + (2 * s + g) * 8];
        const uint2 hi = *(const uint2*)&Vs[cur][dr * 36 + (2 * s + g) * 8 + 4];
        aV.u[0] = lo.x; aV.u[1] = lo.y; aV.u[2] = hi.x; aV.u[3] = hi.y;
        accO[mt] = __builtin_amdgcn_mfma_f32_32x32x16_f16(aV.v, bP.v, accO[mt], 0, 0, 0);
      }
    }

    if (pre) {
      const int nb = cur ^ 1;
      #pragma unroll
      for (int i = 0; i < 2; ++i) {
        const int kr = (tid >> 4) + i * 16;
        *(uint4*)&Ks[nb][kr * 128 + ((tid & 15) ^ (kr & 15)) * 8] = stgK[i];
        const int idx = tid * 2 + i, dr = idx >> 2, cv = idx & 3;
        *(uint2*)&Vs[nb][dr * 36 + cv * 8]     = make_uint2(stgV[i].x, stgV[i].y);
        *(uint2*)&Vs[nb][dr * 36 + cv * 8 + 4] = make_uint2(stgV[i].z, stgV[i].w);
      }
    }
    __syncthreads();
  }

  // epilogue: renormalize to true max, store f16 partial O + (m,l)
  const float scale = exp2f(m_run - m_true);
  const int ncol = n0 + 32 * wv + qlane;
  const size_t obase = (size_t)(b * KSPL + spl) * ICH * NPOS;
  #pragma unroll
  for (int mt = 0; mt < 4; ++mt)
    #pragma unroll
    for (int r = 0; r < 16; ++r) {
      const int d = 32 * mt + (r & 3) + 8 * (r >> 2) + 4 * g;
      Opart[obase + (size_t)d * NPOS + ncol] = f2h(accO[mt][r] * scale);
    }
  if (g == 0) {
    Mpart[(size_t)(b * KSPL + spl) * NPOS + ncol] = m_true;
    Lpart[(size_t)(b * KSPL + spl) * NPOS + ncol] = l_run * scale;
  }
}

// ---------------------------------------------------------------------------
// merge: Y^T[b][d][n] = sum_s 2^{m_s-M} O_s / sum_s 2^{m_s-M} l_s.
// grid (49, 4): x covers 512 n (2/thread), y covers d-chunk of 32 rows.
// ---------------------------------------------------------------------------
__global__ __launch_bounds__(256, 2)
void merge_kernel(const unsigned short* __restrict__ Opart,
                  const float* __restrict__ Mpart,
                  const float* __restrict__ Lpart,
                  float* __restrict__ Yt) {
  const int idx = (blockIdx.x * 256 + threadIdx.x) * 2;   // 0 .. B*N-1 step 2
  const int d0  = blockIdx.y * 32;
  const int b = idx / NPOS, n = idx % NPOS;
  float m[KSPL][2], l[KSPL][2], M0 = -1e30f, M1 = -1e30f;
  #pragma unroll
  for (int s = 0; s < KSPL; ++s) {
    const size_t base = (size_t)(b * KSPL + s) * NPOS + n;
    m[s][0] = Mpart[base]; m[s][1] = Mpart[base + 1];
    l[s][0] = Lpart[base]; l[s][1] = Lpart[base + 1];
    M0 = fmaxf(M0, m[s][0]); M1 = fmaxf(M1, m[s][1]);
  }
  float w[KSPL][2], lt0 = 0.0f, lt1 = 0.0f;
  #pragma unroll
  for (int s = 0; s < KSPL; ++s) {
    w[s][0] = exp2f(m[s][0] - M0); lt0 += w[s][0] * l[s][0];
    w[s][1] = exp2f(m[s][1] - M1); lt1 += w[s][1] * l[s][1];
  }
  const float inv0 = 1.0f / lt0, inv1 = 1.0f / lt1;
  for (int d = d0; d < d0 + 32; ++d) {
    float a0 = 0.0f, a1 = 0.0f;
    #pragma unroll
    for (int s = 0; s < KSPL; ++s) {
      const unsigned int u = *(const unsigned int*)
        &Opart[((size_t)(b * KSPL + s) * ICH + d) * NPOS + n];
      a0 += w[s][0] * (float)__builtin_bit_cast(_Float16, (unsigned short)(u & 0xffff));
      a1 += w[s][1] * (float)__builtin_bit_cast(_Float16, (unsigned short)(u >> 16));
    }
    float2 o; o.x = a0 * inv0; o.y = a1 * inv1;
    *(float2*)&Yt[((size_t)b * ICH + d) * NPOS + n] = o;
  }
}

// ---------------------------------------------------------------------------
// zres: out[b][c][n] = sum_ic Wz[c][ic]*Y^T[b][ic][n] + x. 128x128 block,
// 8x8 thread tile via wave quadrants (both LDS operand reads <=2-way).
// ---------------------------------------------------------------------------
__global__ __launch_bounds__(256, 2)
void zres_kernel(const float* __restrict__ x,
                 const float* __restrict__ Wz,
                 const float* __restrict__ Yt,
                 float* __restrict__ out) {
  const int n0 = blockIdx.x * 128;
  const int c0 = blockIdx.y * 128;
  const int b  = blockIdx.z;
  __shared__ float Yts[16][128];   // [k(ic)][n]
  __shared__ float Wzt[16][128];   // [k][c]
  const int tid = threadIdx.x;
  const int lane = tid & 63, wv = tid >> 6;
  const int tn = lane & 7, tc = lane >> 3;           // 8x8 within wave
  const int nb = (wv & 1) * 64 + tn * 8;             // n offset in block
  const int cb = (wv >> 1) * 64 + tc * 8;            // c offset in block
  float acc[8][8] = {};                              // [c_i][n_j]

  for (int ic0 = 0; ic0 < ICH; ic0 += 16) {
    {
      const int nn = tid & 127, kh = tid >> 7;
      #pragma unroll
      for (int q = 0; q < 8; ++q) {
        const int kk = kh + q * 2;
        Yts[kk][nn] = Yt[((size_t)b * ICH + ic0 + kk) * NPOS + n0 + nn];
      }
      const int wk = tid & 15, wo = tid >> 4;
      #pragma unroll
      for (int q = 0; q < 8; ++q) {
        const int cc = wo + q * 16;
        Wzt[wk][cc] = Wz[(size_t)(c0 + cc) * ICH + ic0 + wk];
      }
    }
    __syncthreads();
    #pragma unroll
    for (int kk = 0; kk < 16; ++kk) {
      const float4 a0 = *(const float4*)&Wzt[kk][cb];
      const float4 a1 = *(const float4*)&Wzt[kk][cb + 4];
      const float4 b0 = *(const float4*)&Yts[kk][nb];
      const float4 b1 = *(const float4*)&Yts[kk][nb + 4];
      const float a_[8] = {a0.x, a0.y, a0.z, a0.w, a1.x, a1.y, a1.z, a1.w};
      const float b_[8] = {b0.x, b0.y, b0.z, b0.w, b1.x, b1.y, b1.z, b1.w};
      #pragma unroll
      for (int i = 0; i < 8; ++i)
        #pragma unroll
        for (int j = 0; j < 8; ++j) acc[i][j] += a_[i] * b_[j];
    }
    __syncthreads();
  }
  #pragma unroll
  for (int i = 0; i < 8; ++i) {
    const size_t base = ((size_t)(b * CCH + c0 + cb + i)) * NPOS + n0 + nb;
    const float4 x0 = *(const float4*)&x[base];
    const float4 x1 = *(const float4*)&x[base + 4];
    float4 v0, v1;
    v0.x = acc[i][0] + x0.x; v0.y = acc[i][1] + x0.y;
    v0.z = acc[i][2] + x0.z; v0.w = acc[i][3] + x0.w;
    v1.x = acc[i][4] + x1.x; v1.y = acc[i][5] + x1.y;
    v1.z = acc[i][6] + x1.z; v1.w = acc[i][7] + x1.w;
    *(float4*)&out[base]     = v0;
    *(float4*)&out[base + 4] = v1;
  }
}

// ---------------------------------------------------------------------------
extern "C" void kernel_launch(void* const* d_in, const int* in_sizes, int n_in,
                              void* d_out, int out_size, void* d_ws, size_t ws_size,
                              hipStream_t stream) {
  const float* x      = (const float*)d_in[0];
  const float* Wg     = (const float*)d_in[1];
  const float* Wtheta = (const float*)d_in[2];
  const float* Wphi   = (const float*)d_in[3];
  const float* Wz     = (const float*)d_in[4];
  float* out = (float*)d_out;

  unsigned short* Qg    = (unsigned short*)d_ws;
  unsigned short* Kg    = Qg + BNIC;
  unsigned short* Vtg   = Kg + BNIC;
  unsigned short* Opart = Vtg + BNIC;                    // KSPL*BNIC ushorts
  float* Mpart = (float*)(Opart + (size_t)KSPL * BNIC);  // KSPL*B*N floats
  float* Lpart = Mpart + (size_t)KSPL * BB * NPOS;       // KSPL*B*N floats
  float* Yt    = (float*)Qg;                             // overlay after flash10

  // Whi/Wlo overlay the Opart region: dead until flash10 writes Opart,
  // and proj_mfma (the only reader) runs before flash10.
  unsigned short* Whi = Opart;                           // 3*128*256 ushorts
  unsigned short* Wlo = Whi + 3 * 128 * 256;

  wconv<<<dim3(96), 256, 0, stream>>>(Wtheta, Wphi, Wg, Whi, Wlo);
  proj_mfma<<<dim3(NPOS / 32, BB), 256, 0, stream>>>(x, Whi, Wlo, Qg, Kg, Vtg);
  flash10 <<<dim3(BB * KSPL * NITK), 256, 0, stream>>>(Qg, Kg, Vtg, Opart, Mpart, Lpart);
  merge_kernel<<<dim3(BB * NPOS / 512, 4), 256, 0, stream>>>(Opart, Mpart, Lpart, Yt);
  zres_kernel<<<dim3(NPOS / 128, CCH / 128, BB), 256, 0, stream>>>(x, Wz, Yt, out);
}

// Round 7
// 316.336 us; speedup vs baseline: 1.5428x; 1.0814x over previous
//
#include <hip/hip_runtime.h>
#include <cstdint>

// SpacetimeNonLocalBlock: B=4, C=256, T*H*W=N=6272, IC=128.
// R14: merge+zres fused into mz_kernel. zres was the last fp32 VALU GEMM
// (1.64 GFLOP, >=10us at 157TF vector peak before staging overhead) and
// merge materialized Yt (12.8MB write + 25.7MB re-read). mz computes per-n
// merge weights once per block, stages merged Y as f16 hi/lo [n][k] tiles
// (B-frag layout proven in proj_mfma), stages Wz hi/lo [c][k] on the fly
// (A-frag), and accumulates with the 3-term hi/lo MFMA (f32-faithful).
// wconv/proj_mfma/flash10 = R13 verbatim (flash plateaued at 186us,
// serial-chain bound; proj MFMA-ization verified absmax-neutral).

#define BB   4
#define CCH  256
#define NPOS 6272
#define ICH  128
#define BNIC ((size_t)BB * NPOS * ICH)
#define KSPL 4
#define KLEN (NPOS / KSPL)   // 1568
#define TKF  32
#define NITK (KLEN / TKF)    // 49
#define SLACK 12.0f

typedef __attribute__((ext_vector_type(8)))  _Float16 h8v;  // 8 f16 MFMA frag
typedef __attribute__((ext_vector_type(16))) float fx16;    // 32x32 acc

__device__ __forceinline__ unsigned short f2h(float f) {
  _Float16 h = (_Float16)f;
  return __builtin_bit_cast(unsigned short, h);
}
__device__ __forceinline__ unsigned int pkh(float lo, float hi) {
  return __builtin_bit_cast(unsigned int, __builtin_amdgcn_cvt_pkrtz(lo, hi));
}
__device__ __forceinline__ float h2f(unsigned short u) {
  return (float)__builtin_bit_cast(_Float16, u);
}

// ---------------------------------------------------------------------------
// wconv: [Wtheta;Wphi;Wg] (3x128x256 f32) -> Whi/Wlo f16 split. grid 96.
// ---------------------------------------------------------------------------
__global__ __launch_bounds__(256, 1)
void wconv(const float* __restrict__ Wtheta, const float* __restrict__ Wphi,
           const float* __restrict__ Wg,
           unsigned short* __restrict__ Whi, unsigned short* __restrict__ Wlo) {
  const int idx4 = (blockIdx.x * 256 + threadIdx.x) * 4;   // [0, 98304) step 4
  const int p = idx4 >> 15;                                // 0,1,2 (128*256=32768)
  const float* W = (p == 0) ? Wtheta : (p == 1) ? Wphi : Wg;
  const float4 v = *(const float4*)&W[idx4 - (p << 15)];
  const float vv[4] = {v.x, v.y, v.z, v.w};
  ushort4 h, l;
  unsigned short* hp = (unsigned short*)&h;
  unsigned short* lp = (unsigned short*)&l;
  #pragma unroll
  for (int q = 0; q < 4; ++q) {
    _Float16 hh = (_Float16)vv[q];
    hp[q] = __builtin_bit_cast(unsigned short, hh);
    lp[q] = f2h(vv[q] - (float)hh);
  }
  *(ushort4*)&Whi[idx4] = h;
  *(ushort4*)&Wlo[idx4] = l;
}

// ---------------------------------------------------------------------------
// proj_mfma: grid (N/32, B), 256 thr (4 waves). Wave wv owns o-tiles
// T = wv*3 + t (t<3): T/4 = proj (0:theta->Qg *log2e, 1:phi->Kg, 2:g->Vtg).
// x chunk [32n][16c] transpose-staged to LDS as f16 hi/lo. 3 MFMA per tile
// per chunk (hi*hi + hi*lo + lo*hi), f32 accum.
// ---------------------------------------------------------------------------
__global__ __launch_bounds__(256, 2)
void proj_mfma(const float* __restrict__ x,
               const unsigned short* __restrict__ Whi,
               const unsigned short* __restrict__ Wlo,
               unsigned short* __restrict__ Qg,
               unsigned short* __restrict__ Kg,
               unsigned short* __restrict__ Vtg) {
  __shared__ unsigned short Xhi[32][24];
  __shared__ unsigned short Xlo[32][24];
  const int n0 = blockIdx.x * 32;
  const int b  = blockIdx.y;
  const int tid = threadIdx.x;
  const int lane = tid & 63, wv = tid >> 6;
  const int ln = lane & 31, g = lane >> 5;

  fx16 acc[3];
  acc[0] = (fx16)(0.0f); acc[1] = (fx16)(0.0f); acc[2] = (fx16)(0.0f);

  const int sn = tid & 31, cp = (tid >> 5) * 2;
  const float* xp = x + ((size_t)b * CCH + cp) * NPOS + n0 + sn;

  float pv0 = xp[0];
  float pv1 = xp[NPOS];

  for (int c0 = 0; c0 < CCH; c0 += 16) {
    {
      _Float16 h0 = (_Float16)pv0, h1 = (_Float16)pv1;
      ushort2 hh, ll;
      hh.x = __builtin_bit_cast(unsigned short, h0);
      hh.y = __builtin_bit_cast(unsigned short, h1);
      ll.x = f2h(pv0 - (float)h0);
      ll.y = f2h(pv1 - (float)h1);
      *(ushort2*)&Xhi[sn][cp] = hh;
      *(ushort2*)&Xlo[sn][cp] = ll;
    }
    if (c0 + 16 < CCH) {
      pv0 = xp[(size_t)(c0 + 16) * NPOS];
      pv1 = xp[(size_t)(c0 + 17) * NPOS];
    }
    __syncthreads();
    const h8v bxh = *(const h8v*)&Xhi[ln][g * 8];
    const h8v bxl = *(const h8v*)&Xlo[ln][g * 8];
    #pragma unroll
    for (int t = 0; t < 3; ++t) {
      const int T = wv * 3 + t;
      const size_t wb = ((size_t)(T * 32 + ln)) * CCH + c0 + g * 8;
      const h8v ah = *(const h8v*)&Whi[wb];
      const h8v al = *(const h8v*)&Wlo[wb];
      acc[t] = __builtin_amdgcn_mfma_f32_32x32x16_f16(ah, bxh, acc[t], 0, 0, 0);
      acc[t] = __builtin_amdgcn_mfma_f32_32x32x16_f16(ah, bxl, acc[t], 0, 0, 0);
      acc[t] = __builtin_amdgcn_mfma_f32_32x32x16_f16(al, bxh, acc[t], 0, 0, 0);
    }
    __syncthreads();
  }

  const float LOG2E = 1.4426950408889634f;
  const int n = n0 + ln;
  #pragma unroll
  for (int t = 0; t < 3; ++t) {
    const int T = wv * 3 + t;
    const int p = T >> 2;
    const int ot = (T & 3) * 32;
    if (p < 2) {
      unsigned short* Out = (p == 0) ? Qg : Kg;
      const float scl = (p == 0) ? LOG2E : 1.0f;
      #pragma unroll
      for (int q = 0; q < 4; ++q) {
        ushort4 v;
        v.x = f2h(acc[t][4 * q + 0] * scl);
        v.y = f2h(acc[t][4 * q + 1] * scl);
        v.z = f2h(acc[t][4 * q + 2] * scl);
        v.w = f2h(acc[t][4 * q + 3] * scl);
        *(ushort4*)&Out[((size_t)b * NPOS + n) * ICH + ot + 8 * q + 4 * g] = v;
      }
    } else {
      #pragma unroll
      for (int r = 0; r < 16; ++r) {
        const int o = ot + (r & 3) + 8 * (r >> 2) + 4 * g;
        Vtg[((size_t)b * ICH + o) * NPOS + n] = f2h(acc[t][r]);
      }
    }
  }
}

// ---------------------------------------------------------------------------
// flash10: EXACT flash5 body; flat grid 784 decoded so XCD k (=f&7) hosts
// K/V slabs {2k,2k+1}. 4 waves, q=32/wave, TK=32, slack-fold softmax,
// tree max. LDS 34 KB: Ks[2][32x128] 4-bit swz, Vs[2][128x36].
// ---------------------------------------------------------------------------
__global__ __launch_bounds__(256, 2)
void flash10(const unsigned short* __restrict__ Qg,
             const unsigned short* __restrict__ Kg,
             const unsigned short* __restrict__ Vtg,
             unsigned short* __restrict__ Opart,
             float* __restrict__ Mpart,
             float* __restrict__ Lpart) {
  __shared__ unsigned short Ks[2][TKF * 128];
  __shared__ unsigned short Vs[2][128 * 36];

  const int f   = blockIdx.x;
  const int xcd = f & 7, j = f >> 3;            // j in [0,98)
  const int hi  = (j >= NITK) ? 1 : 0;
  const int slab = xcd * 2 + hi;                // [0,16)
  const int itile = j - hi * NITK;              // [0,49)
  const int b   = slab >> 2;
  const int spl = slab & 3;
  const int n0  = itile * 128;
  const int kb  = spl * KLEN;

  const int tid = threadIdx.x;
  const int lane = tid & 63, wv = tid >> 6;
  const int qlane = lane & 31, g = lane >> 5;
  const int swz = qlane & 15;

  h8v qf[8];
  {
    const size_t qbase = ((size_t)b * NPOS + n0 + 32 * wv + qlane) * ICH;
    #pragma unroll
    for (int cs = 0; cs < 8; ++cs)
      qf[cs] = *(const h8v*)&Qg[qbase + cs * 16 + g * 8];
  }

  {
    #pragma unroll
    for (int i = 0; i < 2; ++i) {
      const int kr = (tid >> 4) + i * 16, c = tid & 15;
      const uint4 v = *(const uint4*)&Kg[((size_t)b * NPOS + kb + kr) * ICH + c * 8];
      *(uint4*)&Ks[0][kr * 128 + (c ^ (kr & 15)) * 8] = v;
      const int idx = tid * 2 + i, dr = idx >> 2, cv = idx & 3;
      const uint4 w = *(const uint4*)&Vtg[((size_t)b * ICH + dr) * NPOS + kb + cv * 8];
      *(uint2*)&Vs[0][dr * 36 + cv * 8]     = make_uint2(w.x, w.y);
      *(uint2*)&Vs[0][dr * 36 + cv * 8 + 4] = make_uint2(w.z, w.w);
    }
  }
  __syncthreads();

  float m_run = -1e30f, m_true = -1e30f, l_run = 0.0f;
  fx16 accO[4];
  #pragma unroll
  for (int mt = 0; mt < 4; ++mt) accO[mt] = (fx16)(0.0f);

  uint4 stgK[2], stgV[2];

  for (int it = 0; it < NITK; ++it) {
    const int cur = it & 1;
    const bool pre = (it + 1 < NITK);
    if (pre) {
      const int k0n = kb + (it + 1) * TKF;
      #pragma unroll
      for (int i = 0; i < 2; ++i) {
        const int kr = (tid >> 4) + i * 16;
        stgK[i] = *(const uint4*)&Kg[((size_t)b * NPOS + k0n + kr) * ICH + (tid & 15) * 8];
        const int idx = tid * 2 + i, dr = idx >> 2, cv = idx & 3;
        stgV[i] = *(const uint4*)&Vtg[((size_t)b * ICH + dr) * NPOS + k0n + cv * 8];
      }
    }

    // ---- S^T = K . Q^T ----
    fx16 accS = (fx16)(0.0f);
    #pragma unroll
    for (int cs = 0; cs < 8; ++cs) {
      const h8v aK = *(const h8v*)&Ks[cur][qlane * 128 + ((2 * cs + g) ^ swz) * 8];
      accS = __builtin_amdgcn_mfma_f32_32x32x16_f16(aK, qf[cs], accS, 0, 0, 0);
    }

    // ---- slack-fold online softmax (log2 domain), tree max ----
    float a0 = fmaxf(accS[0], accS[1]),   a1 = fmaxf(accS[2], accS[3]);
    float a2 = fmaxf(accS[4], accS[5]),   a3 = fmaxf(accS[6], accS[7]);
    float a4 = fmaxf(accS[8], accS[9]),   a5 = fmaxf(accS[10], accS[11]);
    float a6 = fmaxf(accS[12], accS[13]), a7 = fmaxf(accS[14], accS[15]);
    a0 = fmaxf(a0, a1); a2 = fmaxf(a2, a3); a4 = fmaxf(a4, a5); a6 = fmaxf(a6, a7);
    float mx = fmaxf(fmaxf(a0, a2), fmaxf(a4, a6));
    mx = fmaxf(mx, __shfl_xor(mx, 32));
    m_true = fmaxf(m_true, mx);
    const bool fold = __any(mx > m_run + SLACK);
    const float mn = fold ? fmaxf(m_run, mx) : m_run;
    float lsum = 0.0f;
    unsigned int pk[4][2];
    #pragma unroll
    for (int u = 0; u < 4; ++u) {
      const float p0 = exp2f(accS[4 * u + 0] - mn);
      const float p1 = exp2f(accS[4 * u + 1] - mn);
      const float p2 = exp2f(accS[4 * u + 2] - mn);
      const float p3 = exp2f(accS[4 * u + 3] - mn);
      lsum += (p0 + p1) + (p2 + p3);
      pk[u][0] = pkh(p0, p1);
      pk[u][1] = pkh(p2, p3);
    }
    lsum += __shfl_xor(lsum, 32);
    if (fold) {
      const float alpha = exp2f(m_run - mn);
      l_run = l_run * alpha + lsum;
      m_run = mn;
      #pragma unroll
      for (int mt = 0; mt < 4; ++mt)
        #pragma unroll
        for (int r = 0; r < 16; ++r) accO[mt][r] *= alpha;
    } else {
      l_run += lsum;
    }

    // ---- PV: O^T += V^T . P^T ----
    #pragma unroll
    for (int s = 0; s < 2; ++s) {
      const unsigned int s0 = pk[2 * s + (g ^ 1)][0];
      const unsigned int s1 = pk[2 * s + (g ^ 1)][1];
      const unsigned int t0 = __shfl_xor(s0, 32);
      const unsigned int t1 = __shfl_xor(s1, 32);
      union { unsigned int u[4]; h8v v; } bP;
      bP.u[0] = g ? t0 : pk[2 * s][0];
      bP.u[1] = g ? t1 : pk[2 * s][1];
      bP.u[2] = g ? pk[2 * s + 1][0] : t0;
      bP.u[3] = g ? pk[2 * s + 1][1] : t1;
      #pragma unroll
      for (int mt = 0; mt < 4; ++mt) {
        const int dr = 32 * mt + qlane;
        union { unsigned int u[4]; h8v v; } aV;
        const uint2 lo = *(const uint2*)&Vs[cur][dr * 36 + (2 * s + g) * 8];
        const uint2 hi = *(const uint2*)&Vs[cur][dr * 36 + (2 * s + g) * 8 + 4];
        aV.u[0] = lo.x; aV.u[1] = lo.y; aV.u[2] = hi.x; aV.u[3] = hi.y;
        accO[mt] = __builtin_amdgcn_mfma_f32_32x32x16_f16(aV.v, bP.v, accO[mt], 0, 0, 0);
      }
    }

    if (pre) {
      const int nb = cur ^ 1;
      #pragma unroll
      for (int i = 0; i < 2; ++i) {
        const int kr = (tid >> 4) + i * 16;
        *(uint4*)&Ks[nb][kr * 128 + ((tid & 15) ^ (kr & 15)) * 8] = stgK[i];
        const int idx = tid * 2 + i, dr = idx >> 2, cv = idx & 3;
        *(uint2*)&Vs[nb][dr * 36 + cv * 8]     = make_uint2(stgV[i].x, stgV[i].y);
        *(uint2*)&Vs[nb][dr * 36 + cv * 8 + 4] = make_uint2(stgV[i].z, stgV[i].w);
      }
    }
    __syncthreads();
  }

  // epilogue: renormalize to true max, store f16 partial O + (m,l)
  const float scale = exp2f(m_run - m_true);
  const int ncol = n0 + 32 * wv + qlane;
  const size_t obase = (size_t)(b * KSPL + spl) * ICH * NPOS;
  #pragma unroll
  for (int mt = 0; mt < 4; ++mt)
    #pragma unroll
    for (int r = 0; r < 16; ++r) {
      const int d = 32 * mt + (r & 3) + 8 * (r >> 2) + 4 * g;
      Opart[obase + (size_t)d * NPOS + ncol] = f2h(accO[mt][r] * scale);
    }
  if (g == 0) {
    Mpart[(size_t)(b * KSPL + spl) * NPOS + ncol] = m_true;
    Lpart[(size_t)(b * KSPL + spl) * NPOS + ncol] = l_run * scale;
  }
}

// ---------------------------------------------------------------------------
// mz_kernel: fused merge + zres, MFMA. grid (N/128, C/128=2, B), 256 thr.
// out[b][c][n] = sum_ic Wz[c][ic] * (sum_s ws[n][s]*O_s[ic][n]) + x[b][c][n],
// ws[n][s] = 2^(m_s-M) / sum_s 2^(m_s-M) l_s  (merge weights, per block).
// Y staged as f16 hi/lo [n][k] (B-frag), Wz hi/lo [c][k] (A-frag, converted
// on the fly). 3-term hi/lo MFMA per tile. LDS ~26 KB, 48B rows (b128-ok,
// <=4-way conflicts). Wave wv owns (c-pair wv>>1, n-pair wv&1): 2x2 fx16.
// ---------------------------------------------------------------------------
__global__ __launch_bounds__(256, 2)
void mz_kernel(const float* __restrict__ x,
               const float* __restrict__ Wz,
               const unsigned short* __restrict__ Opart,
               const float* __restrict__ Mpart,
               const float* __restrict__ Lpart,
               float* __restrict__ out) {
  __shared__ float4 wgt[128];
  __shared__ unsigned short Yh[128][24], Yl[128][24];
  __shared__ unsigned short Wzh[128][24], Wzl[128][24];

  const int n0 = blockIdx.x * 128;
  const int c0 = blockIdx.y * 128;
  const int b  = blockIdx.z;
  const int tid = threadIdx.x;
  const int lane = tid & 63, wv = tid >> 6;
  const int ln = lane & 31, g = lane >> 5;

  // ---- phase 0: merge weights for the block's 128 n columns ----
  if (tid < 128) {
    const int n = n0 + tid;
    float m[4], l[4];
    #pragma unroll
    for (int s = 0; s < 4; ++s) {
      m[s] = Mpart[(size_t)(b * KSPL + s) * NPOS + n];
      l[s] = Lpart[(size_t)(b * KSPL + s) * NPOS + n];
    }
    const float M0 = fmaxf(fmaxf(m[0], m[1]), fmaxf(m[2], m[3]));
    float w[4], lt = 0.0f;
    #pragma unroll
    for (int s = 0; s < 4; ++s) { w[s] = exp2f(m[s] - M0); lt += w[s] * l[s]; }
    const float inv = 1.0f / lt;
    float4 o;
    o.x = w[0] * inv; o.y = w[1] * inv; o.z = w[2] * inv; o.w = w[3] * inv;
    wgt[tid] = o;
  }
  __syncthreads();

  // staging coords: n-pair np (n = 2np, 2np+1), ic-group icg (4 ic each)
  const int np  = tid & 63;
  const int icg = tid >> 6;
  const float4 wsA4 = wgt[2 * np];
  const float4 wsB4 = wgt[2 * np + 1];
  const float wA[4] = {wsA4.x, wsA4.y, wsA4.z, wsA4.w};
  const float wB[4] = {wsB4.x, wsB4.y, wsB4.z, wsB4.w};
  // Wz staging coords: row wc, 8-k half wh
  const int wc = tid >> 1, wh = (tid & 1) * 8;
  const float* Wzrow = Wz + (size_t)(c0 + wc) * ICH + wh;
  const int cpair = wv >> 1, npair = wv & 1;

  fx16 acc[2][2];
  acc[0][0] = (fx16)(0.0f); acc[0][1] = (fx16)(0.0f);
  acc[1][0] = (fx16)(0.0f); acc[1][1] = (fx16)(0.0f);

  for (int k0 = 0; k0 < ICH; k0 += 16) {
    // ---- stage Wz chunk hi/lo: [c][k], one b128 write each ----
    {
      const float4 w0 = *(const float4*)&Wzrow[k0];
      const float4 w1 = *(const float4*)&Wzrow[k0 + 4];
      const float wv8[8] = {w0.x, w0.y, w0.z, w0.w, w1.x, w1.y, w1.z, w1.w};
      unsigned int hu[4], lu[4];
      #pragma unroll
      for (int q = 0; q < 4; ++q) {
        _Float16 h0 = (_Float16)wv8[2 * q], h1 = (_Float16)wv8[2 * q + 1];
        hu[q] = (unsigned int)__builtin_bit_cast(unsigned short, h0) |
                ((unsigned int)__builtin_bit_cast(unsigned short, h1) << 16);
        lu[q] = (unsigned int)f2h(wv8[2 * q] - (float)h0) |
                ((unsigned int)f2h(wv8[2 * q + 1] - (float)h1) << 16);
      }
      *(uint4*)&Wzh[wc][wh] = make_uint4(hu[0], hu[1], hu[2], hu[3]);
      *(uint4*)&Wzl[wc][wh] = make_uint4(lu[0], lu[1], lu[2], lu[3]);
    }
    // ---- stage merged Y chunk hi/lo: [n][k] ----
    {
      unsigned short h0a[4], h1a[4], l0a[4], l1a[4];
      #pragma unroll
      for (int j = 0; j < 4; ++j) {
        const int ic = k0 + icg * 4 + j;
        float y0 = 0.0f, y1 = 0.0f;
        #pragma unroll
        for (int s = 0; s < 4; ++s) {
          const unsigned int u = *(const unsigned int*)
            &Opart[((size_t)(b * KSPL + s) * ICH + ic) * NPOS + n0 + 2 * np];
          y0 += wA[s] * h2f((unsigned short)(u & 0xffff));
          y1 += wB[s] * h2f((unsigned short)(u >> 16));
        }
        _Float16 hh0 = (_Float16)y0, hh1 = (_Float16)y1;
        h0a[j] = __builtin_bit_cast(unsigned short, hh0);
        h1a[j] = __builtin_bit_cast(unsigned short, hh1);
        l0a[j] = f2h(y0 - (float)hh0);
        l1a[j] = f2h(y1 - (float)hh1);
      }
      const int kc = icg * 4;
      *(uint2*)&Yh[2 * np][kc] = make_uint2(
        (unsigned)h0a[0] | ((unsigned)h0a[1] << 16),
        (unsigned)h0a[2] | ((unsigned)h0a[3] << 16));
      *(uint2*)&Yh[2 * np + 1][kc] = make_uint2(
        (unsigned)h1a[0] | ((unsigned)h1a[1] << 16),
        (unsigned)h1a[2] | ((unsigned)h1a[3] << 16));
      *(uint2*)&Yl[2 * np][kc] = make_uint2(
        (unsigned)l0a[0] | ((unsigned)l0a[1] << 16),
        (unsigned)l0a[2] | ((unsigned)l0a[3] << 16));
      *(uint2*)&Yl[2 * np + 1][kc] = make_uint2(
        (unsigned)l1a[0] | ((unsigned)l1a[1] << 16),
        (unsigned)l1a[2] | ((unsigned)l1a[3] << 16));
    }
    __syncthreads();

    // ---- MFMA: 2 c-tiles x 2 n-tiles x 3 hi/lo terms ----
    h8v Ah[2], Al[2], Bh[2], Bl[2];
    #pragma unroll
    for (int ci = 0; ci < 2; ++ci) {
      const int cr = (cpair * 2 + ci) * 32 + ln;
      Ah[ci] = *(const h8v*)&Wzh[cr][g * 8];
      Al[ci] = *(const h8v*)&Wzl[cr][g * 8];
    }
    #pragma unroll
    for (int ni = 0; ni < 2; ++ni) {
      const int nr = (npair * 2 + ni) * 32 + ln;
      Bh[ni] = *(const h8v*)&Yh[nr][g * 8];
      Bl[ni] = *(const h8v*)&Yl[nr][g * 8];
    }
    #pragma unroll
    for (int ci = 0; ci < 2; ++ci)
      #pragma unroll
      for (int ni = 0; ni < 2; ++ni) {
        acc[ci][ni] = __builtin_amdgcn_mfma_f32_32x32x16_f16(Ah[ci], Bh[ni], acc[ci][ni], 0, 0, 0);
        acc[ci][ni] = __builtin_amdgcn_mfma_f32_32x32x16_f16(Ah[ci], Bl[ni], acc[ci][ni], 0, 0, 0);
        acc[ci][ni] = __builtin_amdgcn_mfma_f32_32x32x16_f16(Al[ci], Bh[ni], acc[ci][ni], 0, 0, 0);
      }
    __syncthreads();
  }

  // ---- epilogue: out = acc + x ----
  #pragma unroll
  for (int ci = 0; ci < 2; ++ci)
    #pragma unroll
    for (int ni = 0; ni < 2; ++ni) {
      const int n = n0 + npair * 64 + ni * 32 + ln;
      #pragma unroll
      for (int r = 0; r < 16; ++r) {
        const int c = c0 + cpair * 64 + ci * 32 + (r & 3) + 8 * (r >> 2) + 4 * g;
        const size_t base = ((size_t)(b * CCH + c)) * NPOS + n;
        out[base] = acc[ci][ni][r] + x[base];
      }
    }
}

// ---------------------------------------------------------------------------
extern "C" void kernel_launch(void* const* d_in, const int* in_sizes, int n_in,
                              void* d_out, int out_size, void* d_ws, size_t ws_size,
                              hipStream_t stream) {
  const float* x      = (const float*)d_in[0];
  const float* Wg     = (const float*)d_in[1];
  const float* Wtheta = (const float*)d_in[2];
  const float* Wphi   = (const float*)d_in[3];
  const float* Wz     = (const float*)d_in[4];
  float* out = (float*)d_out;

  unsigned short* Qg    = (unsigned short*)d_ws;
  unsigned short* Kg    = Qg + BNIC;
  unsigned short* Vtg   = Kg + BNIC;
  unsigned short* Opart = Vtg + BNIC;                    // KSPL*BNIC ushorts
  float* Mpart = (float*)(Opart + (size_t)KSPL * BNIC);  // KSPL*B*N floats
  float* Lpart = Mpart + (size_t)KSPL * BB * NPOS;       // KSPL*B*N floats

  // Whi/Wlo overlay the Opart region: dead until flash10 writes Opart,
  // and proj_mfma (the only reader) runs before flash10.
  unsigned short* Whi = Opart;                           // 3*128*256 ushorts
  unsigned short* Wlo = Whi + 3 * 128 * 256;

  wconv<<<dim3(96), 256, 0, stream>>>(Wtheta, Wphi, Wg, Whi, Wlo);
  proj_mfma<<<dim3(NPOS / 32, BB), 256, 0, stream>>>(x, Whi, Wlo, Qg, Kg, Vtg);
  flash10 <<<dim3(BB * KSPL * NITK), 256, 0, stream>>>(Qg, Kg, Vtg, Opart, Mpart, Lpart);
  mz_kernel<<<dim3(NPOS / 128, CCH / 128, BB), 256, 0, stream>>>(x, Wz, Opart, Mpart, Lpart, out);
}